// Round 8
// baseline (188.518 us; speedup 1.0000x reference)
//
#include <hip/hip_runtime.h>

#define B_ 4
#define S_ 2048
#define E_ 1024

typedef __attribute__((ext_vector_type(8))) short short8;
typedef __attribute__((ext_vector_type(4))) float f32x4;

__device__ __forceinline__ unsigned short f2bu(float f) {
  unsigned u = __builtin_bit_cast(unsigned, f);
  u = (u + 0x7FFFu + ((u >> 16) & 1u)) >> 16;
  return (unsigned short)u;
}

__device__ __forceinline__ void gload_lds16(const void* g, void* l) {
  __builtin_amdgcn_global_load_lds(
      (const __attribute__((address_space(1))) void*)g,
      (__attribute__((address_space(3))) void*)l, 16, 0, 0);
}

// ---------------- fp32 -> bf16 convert ----------------
__global__ __launch_bounds__(256) void cvt_f32_bf16(
    const float* __restrict__ in, unsigned short* __restrict__ out, int n) {
  int i = blockIdx.x * 256 + threadIdx.x;
  if (i * 4 >= n) return;
  float4 v = ((const float4*)in)[i];
  ushort4 o;
  o.x = f2bu(v.x); o.y = f2bu(v.y); o.z = f2bu(v.z); o.w = f2bu(v.w);
  ((ushort4*)out)[i] = o;
}

__global__ __launch_bounds__(256) void cvt_w3(
    const float* __restrict__ w0, const float* __restrict__ w1,
    const float* __restrict__ w2, unsigned short* __restrict__ out, int n) {
  int z = blockIdx.z;
  const float* in = (z == 0) ? w0 : (z == 1) ? w1 : w2;
  int i = blockIdx.x * 256 + threadIdx.x;
  if (i * 4 >= n) return;
  float4 v = ((const float4*)in)[i];
  ushort4 o;
  o.x = f2bu(v.x); o.y = f2bu(v.y); o.z = f2bu(v.z); o.w = f2bu(v.w);
  ((ushort4*)(out + (long)z * n))[i] = o;
}

// ================= qkv256: m201-geometry deep-pipelined QKV =================
// C[8192][3072] = xb * [Wq;Wk;Wv]^T + bias. BM=BN=256, BK=64, 512 thr
// (8 waves 2Mx4N, wave tile 128x64). LDS 128KB dbuf, XOR-swizzled reads.
// K-loop identical to round 7 (verified). NEW: Q/K blocks compute C^T in
// registers via swapped MFMA operands (mfma(b,a)) so each lane's 4 acc regs
// are 4 consecutive OUTPUT COLUMNS -> ushort4 stores (32/lane) instead of
// 128 scalar 2B stores -> kills the WRITE_SIZE amplification (83.5 vs 50MB).
// acc layout (linear f32x4 acc[32], all indices compile-time):
//   Q/K: acc[cg*8+rg]  cg=colgrp(0..3), rg=rowgrp(0..7)
//        lane: C[row=rg*16+(l&15)][col=cg*16+(l>>4)*4+t4]
//   V:   acc[rg*4+cg]  (original orientation; V stores were already 8B)
__global__ __launch_bounds__(512, 2) void qkv256(
    const unsigned short* __restrict__ A, const unsigned short* __restrict__ W,
    const float* __restrict__ bq, const float* __restrict__ bk,
    const float* __restrict__ bv,
    unsigned short* __restrict__ Qo, unsigned short* __restrict__ Ko,
    unsigned short* __restrict__ Vt) {
  extern __shared__ char smem[];
  constexpr int NT = 16;  // K=1024 / BK=64
  int tid = threadIdx.x;
  int l = tid & 63, w = tid >> 6;
  int wm = w >> 2, wn = w & 3;
  int bid = blockIdx.y * 12 + blockIdx.x;       // 384 blocks, 384%8==0
  int swz = (bid & 7) * 48 + (bid >> 3);        // XCD-bijective swizzle
  int tm = swz / 12, tn = swz % 12;
  bool isqk = (tn >> 2) < 2;                    // block-uniform

  // inverse-swizzled global source column (elements)
  int scol = 8 * ((l & 7) ^ ((l >> 3) & 7));
  const unsigned short* Ag = A + (long)tm * 256 * 1024 + scol;
  const unsigned short* Bg = W + (long)tn * 256 * 1024 + scol;

#define STG_A(tt, h, q)                                                  \
  gload_lds16(Ag + (long)((h) * 128 + (w * 2 + (q)) * 8 + (l >> 3)) * 1024 \
                  + (tt) * 64,                                           \
              smem + ((tt) & 1) * 32768 + (h) * 16384 + (w * 2 + (q)) * 1024)
#define STG_B(tt, h, q)                                                  \
  gload_lds16(Bg + (long)((h) * 128 + (w * 2 + (q)) * 8 + (l >> 3)) * 1024 \
                  + (tt) * 64,                                           \
              smem + 65536 + ((tt) & 1) * 32768 + (h) * 16384 + (w * 2 + (q)) * 1024)

  // swizzled LDS read cols (bytes within 128B row)
  int xorc = (l & 7) << 4;
  int c0 = ((l >> 4) * 16) ^ xorc;       // kk=0
  int c1 = (64 + (l >> 4) * 16) ^ xorc;  // kk=1
  int arow = (wm * 128 + (l & 15)) * 128;
  int brow = (wn * 64 + (l & 15)) * 128;

  f32x4 acc[32] = {};
  short8 a[4][2], b[2][2][2];

  // prologue: tiles 0,1
  STG_A(0, 0, 0); STG_A(0, 0, 1); STG_B(0, 0, 0); STG_B(0, 0, 1);
  STG_B(0, 1, 0); STG_B(0, 1, 1); STG_A(0, 1, 0); STG_A(0, 1, 1);
  STG_A(1, 0, 0); STG_A(1, 0, 1); STG_B(1, 0, 0); STG_B(1, 0, 1);
  STG_B(1, 1, 0); STG_B(1, 1, 1); STG_A(1, 1, 0); STG_A(1, 1, 1);
  asm volatile("s_waitcnt vmcnt(8)" ::: "memory");
  __builtin_amdgcn_s_barrier();

#define BAR_IN                                             \
  asm volatile("" ::: "memory");                           \
  __builtin_amdgcn_s_barrier();                            \
  asm volatile("s_waitcnt lgkmcnt(0)" ::: "memory");       \
  __builtin_amdgcn_sched_barrier(0);                       \
  __builtin_amdgcn_s_setprio(1);
#define BAR_OUT                                            \
  __builtin_amdgcn_s_setprio(0);                           \
  __builtin_amdgcn_sched_barrier(0);                       \
  asm volatile("" ::: "memory");                           \
  __builtin_amdgcn_s_barrier();
// Q/K: swapped operands -> acc holds C^T fragments.
// V:   original orientation.
#define MFMA_Q(MH, NH)                                                    \
  if (isqk) {                                                             \
    _Pragma("unroll")                                                     \
    for (int cf = 0; cf < 2; cf++) {                                      \
      _Pragma("unroll")                                                   \
      for (int rf = 0; rf < 4; rf++) {                                    \
        int ix = ((NH) * 2 + cf) * 8 + (MH) * 4 + rf;                     \
        acc[ix] = __builtin_amdgcn_mfma_f32_16x16x32_bf16(                \
            b[NH][cf][0], a[rf][0], acc[ix], 0, 0, 0);                    \
        acc[ix] = __builtin_amdgcn_mfma_f32_16x16x32_bf16(                \
            b[NH][cf][1], a[rf][1], acc[ix], 0, 0, 0);                    \
      }                                                                   \
    }                                                                     \
  } else {                                                                \
    _Pragma("unroll")                                                     \
    for (int mf = 0; mf < 4; mf++) {                                      \
      _Pragma("unroll")                                                   \
      for (int nf = 0; nf < 2; nf++) {                                    \
        int ix = ((MH) * 4 + mf) * 4 + (NH) * 2 + nf;                     \
        acc[ix] = __builtin_amdgcn_mfma_f32_16x16x32_bf16(                \
            a[mf][0], b[NH][nf][0], acc[ix], 0, 0, 0);                    \
        acc[ix] = __builtin_amdgcn_mfma_f32_16x16x32_bf16(                \
            a[mf][1], b[NH][nf][1], acc[ix], 0, 0, 0);                    \
      }                                                                   \
    }                                                                     \
  }

  for (int t = 0; t < NT; ++t) {
    const char* Ad = smem + (t & 1) * 32768;
    const char* Bd = smem + 65536 + (t & 1) * 32768;

    // ph1: read A-mh0 (8) + B-nh0 (4); compute (0,0)
#pragma unroll
    for (int mf = 0; mf < 4; mf++) {
      a[mf][0] = *(const short8*)(Ad + arow + mf * 2048 + c0);
      a[mf][1] = *(const short8*)(Ad + arow + mf * 2048 + c1);
    }
#pragma unroll
    for (int nf = 0; nf < 2; nf++) {
      b[0][nf][0] = *(const short8*)(Bd + brow + nf * 2048 + c0);
      b[0][nf][1] = *(const short8*)(Bd + brow + nf * 2048 + c1);
    }
    BAR_IN
    MFMA_Q(0, 0)
    BAR_OUT

    // ph2: read B-nh1 (4); compute (0,1)
#pragma unroll
    for (int nf = 0; nf < 2; nf++) {
      b[1][nf][0] = *(const short8*)(Bd + brow + 4096 + nf * 2048 + c0);
      b[1][nf][1] = *(const short8*)(Bd + brow + 4096 + nf * 2048 + c1);
    }
    BAR_IN
    MFMA_Q(0, 1)
    BAR_OUT

    // ph3: read A-mh1 (8); stage B(t+2) x4 (B reads done at ph2 exit);
    //      compute (1,0)
#pragma unroll
    for (int mf = 0; mf < 4; mf++) {
      a[mf][0] = *(const short8*)(Ad + arow + 8192 + mf * 2048 + c0);
      a[mf][1] = *(const short8*)(Ad + arow + 8192 + mf * 2048 + c1);
    }
    if (t + 2 < NT) { STG_B(t + 2, 0, 0); STG_B(t + 2, 0, 1);
                      STG_B(t + 2, 1, 0); STG_B(t + 2, 1, 1); }
    BAR_IN
    MFMA_Q(1, 0)
    BAR_OUT

    // ph4: stage A(t+2) x4 (A reads done at ph3 exit); boundary vmcnt
    //      for tile t+1; compute (1,1)
    if (t + 2 < NT) { STG_A(t + 2, 0, 0); STG_A(t + 2, 0, 1);
                      STG_A(t + 2, 1, 0); STG_A(t + 2, 1, 1); }
    if (t < NT - 2)       asm volatile("s_waitcnt vmcnt(8)" ::: "memory");
    else if (t == NT - 2) asm volatile("s_waitcnt vmcnt(0)" ::: "memory");
    BAR_IN
    MFMA_Q(1, 1)
    BAR_OUT
  }

  // ---------------- epilogue ----------------
  if (isqk) {
    // acc[cg*8+rg] = C^T frag: lane holds C[row=rg*16+(l&15)]
    //                              [col=cg*16+(l>>4)*4 + t4]  -> ushort4
    unsigned short* Ch = (tn >> 2) ? Ko : Qo;
    const float* bias = (tn >> 2) ? bk : bq;
#pragma unroll
    for (int cg = 0; cg < 4; cg++) {
      int gcol = (tn & 3) * 256 + wn * 64 + cg * 16 + (l >> 4) * 4;
      float4 bv4 = *(const float4*)&bias[gcol];
#pragma unroll
      for (int rg = 0; rg < 8; rg++) {
        long grow = (long)tm * 256 + wm * 128 + rg * 16 + (l & 15);
        f32x4 v = acc[cg * 8 + rg];
        ushort4 pk;
        pk.x = f2bu(v[0] + bv4.x);
        pk.y = f2bu(v[1] + bv4.y);
        pk.z = f2bu(v[2] + bv4.z);
        pk.w = f2bu(v[3] + bv4.w);
        *(ushort4*)(Ch + grow * E_ + gcol) = pk;
      }
    }
  } else {
    // V: acc[rg*4+cg], lane holds C[rows r0..r0+3][col] -> Vt[col][r0..r0+3]
    int rh = l >> 4, cl = l & 15;
    long rowbase = (long)tm * 256 + wm * 128 + rh * 4;
    int cmbase = (tn & 3) * 256 + wn * 64 + cl;
#pragma unroll
    for (int cg = 0; cg < 4; cg++) {
      int cm = cmbase + cg * 16;
      float bv_ = bv[cm];
#pragma unroll
      for (int rg = 0; rg < 8; rg++) {
        long r0 = rowbase + rg * 16;
        f32x4 v = acc[rg * 4 + cg];
        ushort4 pk;
        pk.x = f2bu(v[0] + bv_);
        pk.y = f2bu(v[1] + bv_);
        pk.z = f2bu(v[2] + bv_);
        pk.w = f2bu(v[3] + bv_);
        *(ushort4*)(Vt + (long)cm * (B_ * S_) + r0) = pk;
      }
    }
  }
#undef STG_A
#undef STG_B
#undef BAR_IN
#undef BAR_OUT
#undef MFMA_Q
}

// ---------------- B^T GEMM, m97 structure (scores / PV) ----------------
// MODE 1 (SCORES+EXP): lower-tri linear grid (136,1,4); epilogue writes
//                 P' = exp(s/32) bf16 (c<=r else 0) to C0 (lda S_).
// MODE 2 (PV+NORM): A=P' bf16 (lda S_), B=Vt(1024x8192), Keff=(bm+1)*128.
//                 Extra all-ones B-frag accumulates row denom; epilogue divides.
template<int MODE>
__global__ __launch_bounds__(256, 3) void gemm_bt(
    const unsigned short* __restrict__ A, long sAz, int lda,
    const unsigned short* __restrict__ B, long sBz, int ldb,
    void* __restrict__ C0, long sCz, int ldc, int K, float scale) {
  constexpr int BM = 128, BN = 128, BK = 64;
  __shared__ unsigned short lA[BM * BK];
  __shared__ unsigned short lB[BN * BK];
  int bm, bn;
  int bz = blockIdx.z;
  if constexpr (MODE == 1) {
    int t = blockIdx.x;  // 0..135 lower-tri linear
    bm = (int)((sqrtf(8.f * t + 1.f) - 1.f) * 0.5f);
    while ((bm + 1) * (bm + 2) / 2 <= t) bm++;
    while (bm * (bm + 1) / 2 > t) bm--;
    bn = t - bm * (bm + 1) / 2;
  } else {
    bm = blockIdx.y; bn = blockIdx.x;
  }
  const unsigned short* Ab = A + (long)bz * sAz + (long)bm * BM * lda;
  const unsigned short* Bb = B + (long)bz * sBz + (long)bn * BN * ldb;
  int Keff = (MODE == 2) ? min(K, (bm + 1) * BM) : K;

  int tid = threadIdx.x;
  int l = tid & 63, w = tid >> 6;
  int wm = w >> 1, wn = w & 1;

  int srow = l >> 3;
  int schunk = (l & 7) * 8;
  const unsigned short* ga[4];
  const unsigned short* gb[4];
  unsigned short* lad[4];
  unsigned short* lbd[4];
#pragma unroll
  for (int i = 0; i < 4; i++) {
    int seg = i * 4 + w;
    int row = seg * 8 + srow;
    ga[i] = Ab + (long)row * lda + schunk;
    gb[i] = Bb + (long)row * ldb + schunk;
    lad[i] = &lA[seg * 512];
    lbd[i] = &lB[seg * 512];
  }
  int aoff[4], boff[4];
#pragma unroll
  for (int i = 0; i < 4; i++) {
    aoff[i] = (wm * 64 + i * 16 + (l & 15)) * BK + (l >> 4) * 8;
    boff[i] = (wn * 64 + i * 16 + (l & 15)) * BK + (l >> 4) * 8;
  }

  f32x4 acc[4][4] = {};
  f32x4 accd[4] = {};
  short8 ones;
#pragma unroll
  for (int z = 0; z < 8; z++) ones[z] = (short)0x3F80;

  for (int k0 = 0; k0 < Keff; k0 += BK) {
    __syncthreads();
#pragma unroll
    for (int i = 0; i < 4; i++) {
      gload_lds16(ga[i], lad[i]);
      gload_lds16(gb[i], lbd[i]);
    }
#pragma unroll
    for (int i = 0; i < 4; i++) { ga[i] += BK; gb[i] += BK; }
    __syncthreads();
#pragma unroll
    for (int kk = 0; kk < 2; kk++) {
      short8 af[4], bf[4];
#pragma unroll
      for (int i = 0; i < 4; i++) af[i] = *(const short8*)&lA[aoff[i] + kk * 32];
#pragma unroll
      for (int j = 0; j < 4; j++) bf[j] = *(const short8*)&lB[boff[j] + kk * 32];
#pragma unroll
      for (int i = 0; i < 4; i++)
#pragma unroll
        for (int j = 0; j < 4; j++)
          acc[i][j] = __builtin_amdgcn_mfma_f32_16x16x32_bf16(af[i], bf[j], acc[i][j], 0, 0, 0);
      if constexpr (MODE == 2) {
#pragma unroll
        for (int i = 0; i < 4; i++)
          accd[i] = __builtin_amdgcn_mfma_f32_16x16x32_bf16(af[i], ones, accd[i], 0, 0, 0);
      }
    }
  }

  int rh = l >> 4, cl = l & 15;
  long rowbase = (long)bm * BM + wm * 64 + rh * 4;
  int colbase = bn * BN + wn * 64 + cl;

  if constexpr (MODE == 1) {
    unsigned short* Ph = (unsigned short*)C0 + (long)bz * sCz;
#pragma unroll
    for (int j = 0; j < 4; j++) {
      int c = colbase + j * 16;
#pragma unroll
      for (int i = 0; i < 4; i++) {
        int r0 = (int)rowbase + i * 16;
        f32x4 v = acc[i][j];
#pragma unroll
        for (int t = 0; t < 4; t++) {
          int r = r0 + t;
          float p = (c <= r) ? __expf(v[t] * scale) : 0.f;
          Ph[(long)r * ldc + c] = f2bu(p);
        }
      }
    }
  } else {
    float* Cf = (float*)C0 + (long)bz * sCz;
#pragma unroll
    for (int j = 0; j < 4; j++) {
      int c = colbase + j * 16;
#pragma unroll
      for (int i = 0; i < 4; i++) {
        long r0 = rowbase + i * 16;
        f32x4 v = acc[i][j];
        f32x4 d = accd[i];
#pragma unroll
        for (int t = 0; t < 4; t++)
          Cf[(r0 + t) * (long)ldc + c] = v[t] / d[t];
      }
    }
  }
}

// ---------------- host ----------------
extern "C" void kernel_launch(void* const* d_in, const int* in_sizes, int n_in,
                              void* d_out, int out_size, void* d_ws, size_t ws_size,
                              hipStream_t stream) {
  const float* x  = (const float*)d_in[0];
  const float* Wq = (const float*)d_in[2];
  const float* bq = (const float*)d_in[3];
  const float* Wk = (const float*)d_in[4];
  const float* bk = (const float*)d_in[5];
  const float* Wv = (const float*)d_in[6];
  const float* bv = (const float*)d_in[7];
  float* out = (float*)d_out;

  const long NX = (long)B_ * S_ * E_;  // 8388608
  const long NW = (long)E_ * E_;       // 1048576
  unsigned short* xb  = (unsigned short*)d_ws;
  unsigned short* wqb = xb + NX;       // [3072][1024] contiguous (q,k,v)
  unsigned short* Qb  = wqb + 3 * NW;
  unsigned short* Kb  = Qb + NX;
  unsigned short* Vtb = Kb + NX;       // layout [E][B*S]
  unsigned short* Pb  = Vtb + NX;      // [B][S][S] bf16 unnormalized exp-scores

  static int smem_set = 0;
  if (!smem_set) {
    hipFuncSetAttribute((const void*)qkv256,
                        hipFuncAttributeMaxDynamicSharedMemorySize, 131072);
    smem_set = 1;
  }

  cvt_f32_bf16<<<8192, 256, 0, stream>>>(x, xb, (int)NX);
  cvt_w3<<<dim3(1024, 1, 3), 256, 0, stream>>>(Wq, Wk, Wv, wqb, (int)NW);

  // fused QKV, deep pipeline + vectorized C^T epilogue for Q/K
  qkv256<<<dim3(12, 32), 512, 131072, stream>>>(
      xb, wqb, bq, bk, bv, Qb, Kb, Vtb);

  // P' = exp(Q K^T / 32) (causal, bf16), lower-tri linear grid
  gemm_bt<1><<<dim3(136, 1, 4), 256, 0, stream>>>(
      Qb, (long)S_ * E_, E_, Kb, (long)S_ * E_, E_,
      Pb, (long)S_ * S_, S_, E_, 0.03125f);

  // out = (P' V) / rowsum(P') : A = P', B = Vt (N=E, K=S), denom via ones-MFMA
  gemm_bt<2><<<dim3(8, 16, 4), 256, 0, stream>>>(
      Pb, (long)S_ * S_, S_,
      Vtb, (long)S_, B_ * S_,
      out, (long)S_ * E_, E_, S_, 1.f);
}

// Round 9
// 174.935 us; speedup vs baseline: 1.0776x; 1.0776x over previous
//
#include <hip/hip_runtime.h>

#define B_ 4
#define S_ 2048
#define E_ 1024

typedef __attribute__((ext_vector_type(8))) short short8;
typedef __attribute__((ext_vector_type(4))) float f32x4;

__device__ __forceinline__ unsigned short f2bu(float f) {
  unsigned u = __builtin_bit_cast(unsigned, f);
  u = (u + 0x7FFFu + ((u >> 16) & 1u)) >> 16;
  return (unsigned short)u;
}

__device__ __forceinline__ void gload_lds16(const void* g, void* l) {
  __builtin_amdgcn_global_load_lds(
      (const __attribute__((address_space(1))) void*)g,
      (__attribute__((address_space(3))) void*)l, 16, 0, 0);
}

// ---------------- fp32 -> bf16 convert ----------------
__global__ __launch_bounds__(256) void cvt_f32_bf16(
    const float* __restrict__ in, unsigned short* __restrict__ out, int n) {
  int i = blockIdx.x * 256 + threadIdx.x;
  if (i * 4 >= n) return;
  float4 v = ((const float4*)in)[i];
  ushort4 o;
  o.x = f2bu(v.x); o.y = f2bu(v.y); o.z = f2bu(v.z); o.w = f2bu(v.w);
  ((ushort4*)out)[i] = o;
}

__global__ __launch_bounds__(256) void cvt_w3(
    const float* __restrict__ w0, const float* __restrict__ w1,
    const float* __restrict__ w2, unsigned short* __restrict__ out, int n) {
  int z = blockIdx.z;
  const float* in = (z == 0) ? w0 : (z == 1) ? w1 : w2;
  int i = blockIdx.x * 256 + threadIdx.x;
  if (i * 4 >= n) return;
  float4 v = ((const float4*)in)[i];
  ushort4 o;
  o.x = f2bu(v.x); o.y = f2bu(v.y); o.z = f2bu(v.z); o.w = f2bu(v.w);
  ((ushort4*)(out + (long)z * n))[i] = o;
}

// ---------------- zero the softmax denominator buffer ----------------
__global__ __launch_bounds__(256) void zden(float* __restrict__ d) {
  ((float4*)d)[blockIdx.x * 256 + threadIdx.x] = float4{0.f, 0.f, 0.f, 0.f};
}

// ---------------- B^T GEMM, m97 structure, 3 modes ----------------
// MODE 0 (QKV):   A=xb(8192x1024), B=[Wq;Wk;Wv](3072x1024 contiguous bf16).
//                 grid (24,64,1). seg=bn>>3: 0->Q rowmajor, 1->K rowmajor,
//                 2->V transposed [E][B*S]. bias per seg.  [round-4 proven]
// MODE 1 (SCORES+EXP+ROWSUM): lower-tri linear grid (136,1,4); epilogue
//                 writes P' = exp(s/32) bf16 (c<=r else 0) AND atomically
//                 accumulates per-row sums into denom[bz][row].
// MODE 2 (PV):    A=P' bf16 (lda S_), B=Vt(1024x8192), Keff=(bm+1)*128.
//                 No ones-MFMA; epilogue multiplies by 1/denom[row].
template<int MODE>
__global__ __launch_bounds__(256, 3) void gemm_bt(
    const unsigned short* __restrict__ A, long sAz, int lda,
    const unsigned short* __restrict__ B, long sBz, int ldb,
    const float* __restrict__ bias0, const float* __restrict__ bias1,
    const float* __restrict__ bias2,
    void* __restrict__ C0, void* __restrict__ C1, void* __restrict__ C2,
    long sCz, int ldc, int K, float scale, float* __restrict__ denom) {
  constexpr int BM = 128, BN = 128, BK = 64;
  __shared__ unsigned short lA[BM * BK];
  __shared__ unsigned short lB[BN * BK];
  int bm, bn;
  int bz = blockIdx.z;
  if constexpr (MODE == 1) {
    int t = blockIdx.x;  // 0..135 lower-tri linear
    bm = (int)((sqrtf(8.f * t + 1.f) - 1.f) * 0.5f);
    while ((bm + 1) * (bm + 2) / 2 <= t) bm++;
    while (bm * (bm + 1) / 2 > t) bm--;
    bn = t - bm * (bm + 1) / 2;
  } else {
    bm = blockIdx.y; bn = blockIdx.x;
  }
  const unsigned short* Ab = A + (long)bz * sAz + (long)bm * BM * lda;
  const unsigned short* Bb = B + (long)bz * sBz + (long)bn * BN * ldb;
  int Keff = (MODE == 2) ? min(K, (bm + 1) * BM) : K;

  int tid = threadIdx.x;
  int l = tid & 63, w = tid >> 6;
  int wm = w >> 1, wn = w & 1;  // wave computes 64x64 at (wm*64, wn*64)

  // staging: per K-step each 16KB tile = 16 chunks of 1KB (64 lanes x 16B)
  int srow = l >> 3;
  int schunk = (l & 7) * 8;
  const unsigned short* ga[4];
  const unsigned short* gb[4];
  unsigned short* lad[4];
  unsigned short* lbd[4];
#pragma unroll
  for (int i = 0; i < 4; i++) {
    int seg = i * 4 + w;
    int row = seg * 8 + srow;
    ga[i] = Ab + (long)row * lda + schunk;
    gb[i] = Bb + (long)row * ldb + schunk;
    lad[i] = &lA[seg * 512];
    lbd[i] = &lB[seg * 512];
  }
  int aoff[4], boff[4];
#pragma unroll
  for (int i = 0; i < 4; i++) {
    aoff[i] = (wm * 64 + i * 16 + (l & 15)) * BK + (l >> 4) * 8;
    boff[i] = (wn * 64 + i * 16 + (l & 15)) * BK + (l >> 4) * 8;
  }

  f32x4 acc[4][4] = {};

  for (int k0 = 0; k0 < Keff; k0 += BK) {
    __syncthreads();
#pragma unroll
    for (int i = 0; i < 4; i++) {
      gload_lds16(ga[i], lad[i]);
      gload_lds16(gb[i], lbd[i]);
    }
#pragma unroll
    for (int i = 0; i < 4; i++) { ga[i] += BK; gb[i] += BK; }
    __syncthreads();
#pragma unroll
    for (int kk = 0; kk < 2; kk++) {
      short8 af[4], bf[4];
#pragma unroll
      for (int i = 0; i < 4; i++) af[i] = *(const short8*)&lA[aoff[i] + kk * 32];
#pragma unroll
      for (int j = 0; j < 4; j++) bf[j] = *(const short8*)&lB[boff[j] + kk * 32];
#pragma unroll
      for (int i = 0; i < 4; i++)
#pragma unroll
        for (int j = 0; j < 4; j++)
          acc[i][j] = __builtin_amdgcn_mfma_f32_16x16x32_bf16(af[i], bf[j], acc[i][j], 0, 0, 0);
    }
  }

  // epilogue: D col = lane&15, row = (lane>>4)*4 + t   [m89-verified]
  int rh = l >> 4, cl = l & 15;
  long rowbase = (long)bm * BM + wm * 64 + rh * 4;
  int colbase = bn * BN + wn * 64 + cl;

  if constexpr (MODE == 0) {
    int seg = bn >> 3;  // wave-uniform: 0=Q 1=K 2=V
    const float* bias = (seg == 0) ? bias0 : (seg == 1) ? bias1 : bias2;
#pragma unroll
    for (int j = 0; j < 4; j++) {
      int c = colbase + j * 16;
      int cl_ = c & 1023;
      float bv_ = bias[cl_];
#pragma unroll
      for (int i = 0; i < 4; i++) {
        long r0 = rowbase + i * 16;
        f32x4 v = acc[i][j];
        if (seg < 2) {
          unsigned short* Ch = (unsigned short*)((seg == 0) ? C0 : C1);
#pragma unroll
          for (int t = 0; t < 4; t++)
            Ch[(r0 + t) * (long)E_ + cl_] = f2bu(v[t] + bv_);
        } else {
          unsigned short* Vt = (unsigned short*)C2;
          ushort4 pk;
          pk.x = f2bu(v[0] + bv_);
          pk.y = f2bu(v[1] + bv_);
          pk.z = f2bu(v[2] + bv_);
          pk.w = f2bu(v[3] + bv_);
          *(ushort4*)(Vt + (long)cl_ * (B_ * S_) + r0) = pk;
        }
      }
    }
  } else if constexpr (MODE == 1) {
    // P' = exp(s*scale) masked; accumulate row sums -> denom via atomics
    unsigned short* Ph = (unsigned short*)C0 + (long)bz * sCz;
    float rs[4][4] = {};  // [i][t] lane-local row partial sums
#pragma unroll
    for (int j = 0; j < 4; j++) {
      int c = colbase + j * 16;
#pragma unroll
      for (int i = 0; i < 4; i++) {
        int r0 = (int)rowbase + i * 16;
        f32x4 v = acc[i][j];
#pragma unroll
        for (int t = 0; t < 4; t++) {
          int r = r0 + t;
          float p = (c <= r) ? __expf(v[t] * scale) : 0.f;
          Ph[(long)r * ldc + c] = f2bu(p);
          rs[i][t] += p;
        }
      }
    }
    // reduce across the 16 lanes holding the same rows (l&15 = col lanes)
#pragma unroll
    for (int i = 0; i < 4; i++)
#pragma unroll
      for (int t = 0; t < 4; t++) {
        float s = rs[i][t];
        s += __shfl_xor(s, 1);
        s += __shfl_xor(s, 2);
        s += __shfl_xor(s, 4);
        s += __shfl_xor(s, 8);
        rs[i][t] = s;
      }
    if ((l & 15) == 0) {
      float* dz = denom + (long)bz * S_;
#pragma unroll
      for (int i = 0; i < 4; i++)
#pragma unroll
        for (int t = 0; t < 4; t++)
          atomicAdd(&dz[(int)rowbase + i * 16 + t], rs[i][t]);
    }
  } else {
    // out = acc * (1/denom[row])
    float* Cf = (float*)C0 + (long)bz * sCz;
    const float* dz = denom + (long)bz * S_;
    float rdn[4][4];
#pragma unroll
    for (int i = 0; i < 4; i++)
#pragma unroll
      for (int t = 0; t < 4; t++)
        rdn[i][t] = 1.0f / dz[(int)rowbase + i * 16 + t];
#pragma unroll
    for (int j = 0; j < 4; j++) {
      int c = colbase + j * 16;
#pragma unroll
      for (int i = 0; i < 4; i++) {
        long r0 = rowbase + i * 16;
        f32x4 v = acc[i][j];
#pragma unroll
        for (int t = 0; t < 4; t++)
          Cf[(r0 + t) * (long)ldc + c] = v[t] * rdn[i][t];
      }
    }
  }
}

// ---------------- host ----------------
extern "C" void kernel_launch(void* const* d_in, const int* in_sizes, int n_in,
                              void* d_out, int out_size, void* d_ws, size_t ws_size,
                              hipStream_t stream) {
  const float* x  = (const float*)d_in[0];
  const float* Wq = (const float*)d_in[2];
  const float* bq = (const float*)d_in[3];
  const float* Wk = (const float*)d_in[4];
  const float* bk = (const float*)d_in[5];
  const float* Wv = (const float*)d_in[6];
  const float* bv = (const float*)d_in[7];
  float* out = (float*)d_out;

  const long NX = (long)B_ * S_ * E_;  // 8388608
  const long NW = (long)E_ * E_;       // 1048576
  unsigned short* xb  = (unsigned short*)d_ws;
  unsigned short* wqb = xb + NX;       // [3072][1024] contiguous (q,k,v)
  unsigned short* Qb  = wqb + 3 * NW;
  unsigned short* Kb  = Qb + NX;
  unsigned short* Vtb = Kb + NX;       // layout [E][B*S]
  unsigned short* Pb  = Vtb + NX;      // [B][S][S] bf16 unnormalized exp-scores
  float* denom = (float*)(Pb + (long)B_ * S_ * S_);  // [B][S] fp32 row sums

  cvt_f32_bf16<<<8192, 256, 0, stream>>>(x, xb, (int)NX);
  cvt_w3<<<dim3(1024, 1, 3), 256, 0, stream>>>(Wq, Wk, Wv, wqb, (int)NW);
  zden<<<8, 256, 0, stream>>>(denom);

  // fused QKV: A=xb, B=[Wq;Wk;Wv] (3072x1024), N=3072  [round-4 proven]
  gemm_bt<0><<<dim3(24, 64, 1), 256, 0, stream>>>(
      xb, 0, E_, wqb, 0, E_, bq, bk, bv,
      Qb, Kb, Vtb, 0, E_, E_, 1.f, nullptr);

  // P' = exp(Q K^T / 32) (causal, bf16) + rowsum atomics, lower-tri grid
  gemm_bt<1><<<dim3(136, 1, 4), 256, 0, stream>>>(
      Qb, (long)S_ * E_, E_, Kb, (long)S_ * E_, E_, nullptr, nullptr, nullptr,
      Pb, nullptr, nullptr, (long)S_ * S_, S_, E_, 0.03125f, denom);

  // out = (P' V) * (1/denom) : A = P', B = Vt (N=E, K=S)
  gemm_bt<2><<<dim3(8, 16, 4), 256, 0, stream>>>(
      Pb, (long)S_ * S_, S_,
      Vtb, (long)S_, B_ * S_, nullptr, nullptr, nullptr,
      out, nullptr, nullptr, (long)S_ * E_, E_, S_, 1.f, denom);
}

// Round 10
// 165.258 us; speedup vs baseline: 1.1408x; 1.0586x over previous
//
#include <hip/hip_runtime.h>

#define B_ 4
#define S_ 2048
#define E_ 1024

typedef __attribute__((ext_vector_type(8))) short short8;
typedef __attribute__((ext_vector_type(4))) float f32x4;

__device__ __forceinline__ unsigned short f2bu(float f) {
  unsigned u = __builtin_bit_cast(unsigned, f);
  u = (u + 0x7FFFu + ((u >> 16) & 1u)) >> 16;
  return (unsigned short)u;
}

__device__ __forceinline__ void gload_lds16(const void* g, void* l) {
  __builtin_amdgcn_global_load_lds(
      (const __attribute__((address_space(1))) void*)g,
      (__attribute__((address_space(3))) void*)l, 16, 0, 0);
}

// ---------------- fp32 -> bf16 convert ----------------
__global__ __launch_bounds__(256) void cvt_f32_bf16(
    const float* __restrict__ in, unsigned short* __restrict__ out, int n) {
  int i = blockIdx.x * 256 + threadIdx.x;
  if (i * 4 >= n) return;
  float4 v = ((const float4*)in)[i];
  ushort4 o;
  o.x = f2bu(v.x); o.y = f2bu(v.y); o.z = f2bu(v.z); o.w = f2bu(v.w);
  ((ushort4*)out)[i] = o;
}

__global__ __launch_bounds__(256) void cvt_w3(
    const float* __restrict__ w0, const float* __restrict__ w1,
    const float* __restrict__ w2, unsigned short* __restrict__ out, int n) {
  int z = blockIdx.z;
  const float* in = (z == 0) ? w0 : (z == 1) ? w1 : w2;
  int i = blockIdx.x * 256 + threadIdx.x;
  if (i * 4 >= n) return;
  float4 v = ((const float4*)in)[i];
  ushort4 o;
  o.x = f2bu(v.x); o.y = f2bu(v.y); o.z = f2bu(v.z); o.w = f2bu(v.w);
  ((ushort4*)(out + (long)z * n))[i] = o;
}

// ---------------- zero the softmax denominator buffer ----------------
__global__ __launch_bounds__(256) void zden(float* __restrict__ d) {
  ((float4*)d)[blockIdx.x * 256 + threadIdx.x] = float4{0.f, 0.f, 0.f, 0.f};
}

// ---------------- shared m97-structure GEMM body ----------------
// MODE 0 (QKV): C = A*W^T+bias routed Q/K rowmajor, V transposed.
// MODE 1 (SCORES): P' = exp(s/32) bf16 causal + rowsum atomics into denom.
// MODE 2 (PV): out = acc * 1/denom[row], Keff = (bm+1)*128.
template<int MODE>
__device__ __forceinline__ void gemm_body(
    const unsigned short* __restrict__ A, long sAz, int lda,
    const unsigned short* __restrict__ B, long sBz, int ldb,
    const float* __restrict__ bias0, const float* __restrict__ bias1,
    const float* __restrict__ bias2,
    void* __restrict__ C0, void* __restrict__ C1, void* __restrict__ C2,
    long sCz, int ldc, int K, float scale, float* __restrict__ denom,
    unsigned short* lA, unsigned short* lB, int bm, int bn, int bz) {
  constexpr int BK = 64;
  const unsigned short* Ab = A + (long)bz * sAz + (long)bm * 128 * lda;
  const unsigned short* Bb = B + (long)bz * sBz + (long)bn * 128 * ldb;
  int Keff = (MODE == 2) ? min(K, (bm + 1) * 128) : K;

  int tid = threadIdx.x;
  int l = tid & 63, w = tid >> 6;
  int wm = w >> 1, wn = w & 1;  // wave computes 64x64 at (wm*64, wn*64)

  int srow = l >> 3;
  int schunk = (l & 7) * 8;
  const unsigned short* ga[4];
  const unsigned short* gb[4];
  unsigned short* lad[4];
  unsigned short* lbd[4];
#pragma unroll
  for (int i = 0; i < 4; i++) {
    int seg = i * 4 + w;
    int row = seg * 8 + srow;
    ga[i] = Ab + (long)row * lda + schunk;
    gb[i] = Bb + (long)row * ldb + schunk;
    lad[i] = &lA[seg * 512];
    lbd[i] = &lB[seg * 512];
  }
  int aoff[4], boff[4];
#pragma unroll
  for (int i = 0; i < 4; i++) {
    aoff[i] = (wm * 64 + i * 16 + (l & 15)) * BK + (l >> 4) * 8;
    boff[i] = (wn * 64 + i * 16 + (l & 15)) * BK + (l >> 4) * 8;
  }

  f32x4 acc[4][4] = {};

  for (int k0 = 0; k0 < Keff; k0 += BK) {
    __syncthreads();
#pragma unroll
    for (int i = 0; i < 4; i++) {
      gload_lds16(ga[i], lad[i]);
      gload_lds16(gb[i], lbd[i]);
    }
#pragma unroll
    for (int i = 0; i < 4; i++) { ga[i] += BK; gb[i] += BK; }
    __syncthreads();
#pragma unroll
    for (int kk = 0; kk < 2; kk++) {
      short8 af[4], bf[4];
#pragma unroll
      for (int i = 0; i < 4; i++) af[i] = *(const short8*)&lA[aoff[i] + kk * 32];
#pragma unroll
      for (int j = 0; j < 4; j++) bf[j] = *(const short8*)&lB[boff[j] + kk * 32];
#pragma unroll
      for (int i = 0; i < 4; i++)
#pragma unroll
        for (int j = 0; j < 4; j++)
          acc[i][j] = __builtin_amdgcn_mfma_f32_16x16x32_bf16(af[i], bf[j], acc[i][j], 0, 0, 0);
    }
  }

  // epilogue: D col = lane&15, row = (lane>>4)*4 + t   [m89-verified]
  int rh = l >> 4, cl = l & 15;
  long rowbase = (long)bm * 128 + wm * 64 + rh * 4;
  int colbase = bn * 128 + wn * 64 + cl;

  if constexpr (MODE == 0) {
    int seg = bn >> 3;  // wave-uniform: 0=Q 1=K 2=V
    const float* bias = (seg == 0) ? bias0 : (seg == 1) ? bias1 : bias2;
#pragma unroll
    for (int j = 0; j < 4; j++) {
      int c = colbase + j * 16;
      int cl_ = c & 1023;
      float bv_ = bias[cl_];
#pragma unroll
      for (int i = 0; i < 4; i++) {
        long r0 = rowbase + i * 16;
        f32x4 v = acc[i][j];
        if (seg < 2) {
          unsigned short* Ch = (unsigned short*)((seg == 0) ? C0 : C1);
#pragma unroll
          for (int t = 0; t < 4; t++)
            Ch[(r0 + t) * (long)E_ + cl_] = f2bu(v[t] + bv_);
        } else {
          unsigned short* Vt = (unsigned short*)C2;
          ushort4 pk;
          pk.x = f2bu(v[0] + bv_);
          pk.y = f2bu(v[1] + bv_);
          pk.z = f2bu(v[2] + bv_);
          pk.w = f2bu(v[3] + bv_);
          *(ushort4*)(Vt + (long)cl_ * (B_ * S_) + r0) = pk;
        }
      }
    }
  } else if constexpr (MODE == 1) {
    // P' = exp(s*scale) masked; j INNERMOST so each lane's 4 stores to a
    // row's 128B span issue back-to-back (write-combine; round-7 lesson).
    unsigned short* Ph = (unsigned short*)C0 + (long)bz * sCz;
    float rs[4][4] = {};
#pragma unroll
    for (int i = 0; i < 4; i++) {
      int r0 = (int)rowbase + i * 16;
#pragma unroll
      for (int t = 0; t < 4; t++) {
        int r = r0 + t;
#pragma unroll
        for (int j = 0; j < 4; j++) {
          int c = colbase + j * 16;
          float p = (c <= r) ? __expf(acc[i][j][t] * scale) : 0.f;
          Ph[(long)r * ldc + c] = f2bu(p);
          rs[i][t] += p;
        }
      }
    }
#pragma unroll
    for (int i = 0; i < 4; i++)
#pragma unroll
      for (int t = 0; t < 4; t++) {
        float s = rs[i][t];
        s += __shfl_xor(s, 1);
        s += __shfl_xor(s, 2);
        s += __shfl_xor(s, 4);
        s += __shfl_xor(s, 8);
        rs[i][t] = s;
      }
    if ((l & 15) == 0) {
      float* dz = denom + (long)bz * S_;
#pragma unroll
      for (int i = 0; i < 4; i++)
#pragma unroll
        for (int t = 0; t < 4; t++)
          atomicAdd(&dz[(int)rowbase + i * 16 + t], rs[i][t]);
    }
  } else {
    float* Cf = (float*)C0 + (long)bz * sCz;
    const float* dz = denom + (long)bz * S_;
    float rdn[4][4];
#pragma unroll
    for (int i = 0; i < 4; i++)
#pragma unroll
      for (int t = 0; t < 4; t++)
        rdn[i][t] = 1.0f / dz[(int)rowbase + i * 16 + t];
#pragma unroll
    for (int j = 0; j < 4; j++) {
      int c = colbase + j * 16;
#pragma unroll
      for (int i = 0; i < 4; i++) {
        long r0 = rowbase + i * 16;
        f32x4 v = acc[i][j];
#pragma unroll
        for (int t = 0; t < 4; t++)
          Cf[(r0 + t) * (long)ldc + c] = v[t] * rdn[i][t];
      }
    }
  }
}

// ---------------- named kernels ----------------
// QKV: grid (24,64); XCD bm-chunked swizzle (1536 = 8 x 192) so each XCD's
// L2 streams 1/8 of x once instead of round-robin re-fetch.
__global__ __launch_bounds__(256, 3) void k_qkv(
    const unsigned short* __restrict__ A, const unsigned short* __restrict__ W,
    const float* __restrict__ bq, const float* __restrict__ bk,
    const float* __restrict__ bv,
    unsigned short* __restrict__ Qo, unsigned short* __restrict__ Ko,
    unsigned short* __restrict__ Vt) {
  __shared__ unsigned short lA[128 * 64];
  __shared__ unsigned short lB[128 * 64];
  int bid = blockIdx.y * 24 + blockIdx.x;
  int nb = (bid & 7) * 192 + (bid >> 3);
  gemm_body<0>(A, 0, E_, W, 0, E_, bq, bk, bv, Qo, Ko, Vt,
               0, E_, E_, 1.f, nullptr, lA, lB, nb / 24, nb % 24, 0);
}

// SCORES: lower-tri linear grid (136,1,4); XCD-chunked (136 = 8 x 17) so
// same-bm tiles (shared Q panel) land on one XCD's L2.
__global__ __launch_bounds__(256, 3) void k_scores(
    const unsigned short* __restrict__ Q, const unsigned short* __restrict__ K,
    unsigned short* __restrict__ P, float* __restrict__ denom) {
  __shared__ unsigned short lA[128 * 64];
  __shared__ unsigned short lB[128 * 64];
  int t0 = blockIdx.x;
  int t = (t0 & 7) * 17 + (t0 >> 3);
  int bm = (int)((sqrtf(8.f * t + 1.f) - 1.f) * 0.5f);
  while ((bm + 1) * (bm + 2) / 2 <= t) bm++;
  while (bm * (bm + 1) / 2 > t) bm--;
  int bn = t - bm * (bm + 1) / 2;
  gemm_body<1>(Q, (long)S_ * E_, E_, K, (long)S_ * E_, E_,
               nullptr, nullptr, nullptr, P, nullptr, nullptr,
               (long)S_ * S_, S_, E_, 0.03125f, denom,
               lA, lB, bm, bn, blockIdx.z);
}

// PV: grid (8,16,4); bm DESCENDING so the 16-K-step blocks launch first and
// short blocks backfill (longest-first packing; Keff varies 16:1).
__global__ __launch_bounds__(256, 3) void k_pv(
    const unsigned short* __restrict__ P, const unsigned short* __restrict__ Vt,
    float* __restrict__ out, const float* __restrict__ denom) {
  __shared__ unsigned short lA[128 * 64];
  __shared__ unsigned short lB[128 * 64];
  int bm = 15 - blockIdx.y;
  gemm_body<2>(P, (long)S_ * S_, S_, Vt, (long)S_, B_ * S_,
               nullptr, nullptr, nullptr, out, nullptr, nullptr,
               (long)S_ * E_, E_, S_, 1.f, (float*)denom,
               lA, lB, bm, blockIdx.x, blockIdx.z);
}

// ---------------- host ----------------
extern "C" void kernel_launch(void* const* d_in, const int* in_sizes, int n_in,
                              void* d_out, int out_size, void* d_ws, size_t ws_size,
                              hipStream_t stream) {
  const float* x  = (const float*)d_in[0];
  const float* Wq = (const float*)d_in[2];
  const float* bq = (const float*)d_in[3];
  const float* Wk = (const float*)d_in[4];
  const float* bk = (const float*)d_in[5];
  const float* Wv = (const float*)d_in[6];
  const float* bv = (const float*)d_in[7];
  float* out = (float*)d_out;

  const long NX = (long)B_ * S_ * E_;  // 8388608
  const long NW = (long)E_ * E_;       // 1048576
  unsigned short* xb  = (unsigned short*)d_ws;
  unsigned short* wqb = xb + NX;       // [3072][1024] contiguous (q,k,v)
  unsigned short* Qb  = wqb + 3 * NW;
  unsigned short* Kb  = Qb + NX;
  unsigned short* Vtb = Kb + NX;       // layout [E][B*S]
  unsigned short* Pb  = Vtb + NX;      // [B][S][S] bf16 unnormalized exp-scores
  float* denom = (float*)(Pb + (long)B_ * S_ * S_);  // [B][S] fp32 row sums

  cvt_f32_bf16<<<8192, 256, 0, stream>>>(x, xb, (int)NX);
  cvt_w3<<<dim3(1024, 1, 3), 256, 0, stream>>>(Wq, Wk, Wv, wqb, (int)NW);
  zden<<<8, 256, 0, stream>>>(denom);

  k_qkv<<<dim3(24, 64), 256, 0, stream>>>(xb, wqb, bq, bk, bv, Qb, Kb, Vtb);

  k_scores<<<dim3(136, 1, 4), 256, 0, stream>>>(Qb, Kb, Pb, denom);

  k_pv<<<dim3(8, 16, 4), 256, 0, stream>>>(Pb, Vtb, out, denom);
}